// Round 2
// baseline (74.612 us; speedup 1.0000x reference)
//
#include <hip/hip_runtime.h>
#include <cstdint>
#include <cstddef>

// ---------------------------------------------------------------------------
// Problem constants
// ---------------------------------------------------------------------------
#define BB 2
#define PP 4
#define CC 3
#define HH 256
#define WW 256
#define HWSZ 65536            // H*W
#define BGH 2764
#define BGW 3856
#define NTAO 27               // life has 3 entries x 9 linspace points
#define X4_SIZE (BB*PP*HWSZ)              // 524288
#define TAO_OFF X4_SIZE
#define TAO_SIZE (BB*NTAO*HWSZ)           // 3538944
#define OUT2_OFF (TAO_OFF + TAO_SIZE)     // 4063232
#define NCH 40                            // poisson knuth chain depth

// Flip to 0 if the harness JAX uses the legacy (non-partitionable) threefry
#define JAX_PARTITIONABLE 1

// ---------------------------------------------------------------------------
// Threefry-2x32-20 (matches jax/_src/prng.py)
// ---------------------------------------------------------------------------
__host__ __device__ inline void tf2x32(uint32_t k0, uint32_t k1,
                                       uint32_t x0, uint32_t x1,
                                       uint32_t& o0, uint32_t& o1) {
  uint32_t ks2 = k0 ^ k1 ^ 0x1BD11BDAu;
  x0 += k0; x1 += k1;
#define TF_RND(r) { x0 += x1; x1 = (x1 << (r)) | (x1 >> (32 - (r))); x1 ^= x0; }
  TF_RND(13) TF_RND(15) TF_RND(26) TF_RND(6)
  x0 += k1;  x1 += ks2 + 1u;
  TF_RND(17) TF_RND(29) TF_RND(16) TF_RND(24)
  x0 += ks2; x1 += k0 + 2u;
  TF_RND(13) TF_RND(15) TF_RND(26) TF_RND(6)
  x0 += k0;  x1 += k1 + 3u;
  TF_RND(17) TF_RND(29) TF_RND(16) TF_RND(24)
  x0 += k1;  x1 += ks2 + 4u;
  TF_RND(13) TF_RND(15) TF_RND(26) TF_RND(6)
  x0 += ks2; x1 += k0 + 5u;
#undef TF_RND
  o0 = x0; o1 = x1;
}

// 32-bit random bits for flat element e of an n-element draw (random_bits).
__host__ __device__ inline uint32_t bits32(uint32_t k0, uint32_t k1,
                                           uint32_t e, uint32_t n) {
#if JAX_PARTITIONABLE
  (void)n;
  uint32_t o0, o1;
  tf2x32(k0, k1, 0u, e, o0, o1);     // counts = (hi,lo) of 64-bit flat iota
  return o0 ^ o1;                     // 32-bit path: bits1 ^ bits2
#else
  uint32_t half = n >> 1;
  uint32_t o0, o1;
  if (e < half) { tf2x32(k0, k1, e, e + half, o0, o1); return o0; }
  else          { tf2x32(k0, k1, e - half, e, o0, o1); return o1; }
#endif
}

// jax.random.split(key, n) -> n subkeys. NOTE: partitionable split is
// _threefry_split_foldlike: subkey i = RAW pair threefry(key, (0, i)),
// NOT the xor-folded random_bits((n,2)).
static void jax_split(uint32_t k0, uint32_t k1, int n, uint32_t (*keys)[2]) {
#if JAX_PARTITIONABLE
  for (int i = 0; i < n; ++i)
    tf2x32(k0, k1, 0u, (uint32_t)i, keys[i][0], keys[i][1]);
#else
  // legacy: counts = iota(2n) split into halves (j, n+j)
  uint32_t res[64];
  for (int j = 0; j < n; ++j) {
    uint32_t o0, o1;
    tf2x32(k0, k1, (uint32_t)j, (uint32_t)(n + j), o0, o1);
    res[j] = o0; res[n + j] = o1;
  }
  for (int i = 0; i < n; ++i) { keys[i][0] = res[2*i]; keys[i][1] = res[2*i+1]; }
#endif
}

// bits -> float in [0,1)  (jax _uniform: (bits>>9)|0x3f800000, bitcast, -1)
__host__ __device__ inline float u01(uint32_t bits) {
  uint32_t fb = (bits >> 9) | 0x3F800000u;
  return __builtin_bit_cast(float, fb) - 1.0f;
}

// ---------------------------------------------------------------------------
// erfinv (Giles single-precision poly == XLA ErfInv32, w = -log1p(-x*x))
// ---------------------------------------------------------------------------
__device__ inline float erfinv_f(float x) {
  float w = -log1pf(-x * x);
  float p;
  if (w < 5.0f) {
    w = w - 2.5f;
    p = 2.81022636e-08f;
    p = fmaf(p, w, 3.43273939e-07f);
    p = fmaf(p, w, -3.5233877e-06f);
    p = fmaf(p, w, -4.39150654e-06f);
    p = fmaf(p, w, 0.00021858087f);
    p = fmaf(p, w, -0.00125372503f);
    p = fmaf(p, w, -0.00417768164f);
    p = fmaf(p, w, 0.246640727f);
    p = fmaf(p, w, 1.50140941f);
  } else {
    w = sqrtf(w) - 3.0f;
    p = -0.000200214257f;
    p = fmaf(p, w, 0.000100950558f);
    p = fmaf(p, w, 0.00134934322f);
    p = fmaf(p, w, -0.00367342844f);
    p = fmaf(p, w, 0.00573950773f);
    p = fmaf(p, w, -0.0076224613f);
    p = fmaf(p, w, 0.00943887047f);
    p = fmaf(p, w, 1.00167406f);
    p = fmaf(p, w, 2.83297682f);
  }
  return p * x;
}

// jax.random.normal: u = max(lo, f*(hi-lo)+lo), lo = nextafter(-1,0); sqrt2*erfinv
__device__ inline float normal_e(uint32_t k0, uint32_t k1, uint32_t e, uint32_t n) {
  float f = u01(bits32(k0, k1, e, n));
  const float LO = -0.99999994f;      // 0xBF7FFFFF
  const float SPAN = 2.0f;            // fp32(1.0f - LO) == 2.0f exactly
  float u = fmaxf(LO, fmaf(f, SPAN, LO));
  return 1.41421356237f * erfinv_f(u);   // fp32 sqrt(2) = 0x3FB504F3
}

// ---------------------------------------------------------------------------
// Poisson via Knuth (matches jax _poisson_knuth, per-element early exit)
// subkeys laid out as [i] -> (sk[2i], sk[2i+1]); u drawn from X4_SIZE stream
// ---------------------------------------------------------------------------
__device__ inline int knuth_poisson(const uint32_t* __restrict__ sk,
                                    uint32_t e, float lam) {
  if (!(lam > 0.0f)) return 0;        // jax: where(lam == 0, 0, ...)
  const float neg = -lam;
  float lp = 0.0f;
  int k = 0;
  for (int i = 0; i < NCH; ++i) {
    if (!(lp > neg)) break;
    k++;
    float u = u01(bits32(sk[2*i], sk[2*i+1], e, (uint32_t)X4_SIZE));
    lp += logf(u);
  }
  return k - 1;
}

// ---------------------------------------------------------------------------
// Kernel params
// ---------------------------------------------------------------------------
struct PCParams {
  uint32_t kn0, kn1;        // k_norm
  uint32_t kb0, kb1;        // k_bgn
  uint32_t s1[NCH * 2];     // poisson chain subkeys for k_p1
  uint32_t s2[NCH * 2];     // poisson chain subkeys for k_p2
  float bg1[8], bg2[8];
  int idx;
};

// ---------------------------------------------------------------------------
// Init: zero the global-max slot, emit outputs 2 (t*ratio) and 3 (ratio)
// ---------------------------------------------------------------------------
__global__ void kInit(const float* __restrict__ t, const float* __restrict__ ratio,
                      float* __restrict__ out, unsigned int* __restrict__ wsmax) {
  int i = threadIdx.x;
  if (i == 0) *wsmax = 0u;
  if (i < 4)       out[OUT2_OFF + i] = t[i] * ratio[i];
  else if (i < 8)  out[OUT2_OFF + i] = ratio[i - 4];
}

// ---------------------------------------------------------------------------
// Kernel A: decay weights -> tao_gt + x2 (+ global max of x2)
// one thread per (b, h, w); loops p(4) x c(3) x tao(27)
// ---------------------------------------------------------------------------
__global__ __launch_bounds__(256) void kA(
    const float* __restrict__ x, const float* __restrict__ t,
    const float* __restrict__ ratio, const float* __restrict__ life,
    const float* __restrict__ inten, float* __restrict__ out,
    unsigned int* __restrict__ wsmax,
    uint32_t kl0, uint32_t kl1, uint32_t ks0, uint32_t ks1) {
  __shared__ float tao_s[NTAO];
  __shared__ float et_s[NTAO][4];
  const int tid = threadIdx.x;
  if (tid < NTAO * 4) {
    int j = tid >> 2, p = tid & 3;
    float tao = life[j / 9] + (-40.0f + 10.0f * (float)(j % 9));
    float Tp = fmaxf(t[p] * ratio[p] * 1000.0f, 0.0f);
    et_s[j][p] = expf((-Tp) / tao);
    if (p == 0) tao_s[j] = tao;
  }
  __syncthreads();

  const int g = blockIdx.x * 256 + tid;     // [0, 131072)
  const int b = g >> 16;
  const int hw = g & 0xFFFF;

  float tg[NTAO];
#pragma unroll
  for (int j = 0; j < NTAO; ++j) tg[j] = 0.0f;
  float mloc = 0.0f;

#pragma unroll
  for (int p = 0; p < 4; ++p) {
    float acc = 0.0f;
#pragma unroll
    for (int c = 0; c < 3; ++c) {
      const uint32_t e = (uint32_t)((((b * 4 + p) * 3 + c) << 16) + hw);
      const uint32_t NLS = (uint32_t)(BB * PP * CC * HWSZ);   // 1572864
      float ul = u01(bits32(kl0, kl1, e, NLS));
      float Lr = life[c] + ((ul - 0.5f) * 2.0f) * 6.0f;
      float us = u01(bits32(ks0, ks1, e, NLS));
      float sr = 6.0f + (((us - 0.5f) * 2.0f) * 6.0f) * 0.05f;
      float inv = 1.0f / (2.0f * sr * sr);
      float q[NTAO];
      float s = 0.0f;
#pragma unroll
      for (int j = 0; j < NTAO; ++j) {
        float d = tao_s[j] - Lr;
        q[j] = expf(-(d * d) * inv);
        s += q[j];
      }
      float rs = 1.0f / s;
      float dec = 0.0f;
#pragma unroll
      for (int j = 0; j < NTAO; ++j) {
        float wn = q[j] * rs;
        tg[j] += wn;
        dec += et_s[j][p] * wn;
      }
      acc += x[e] * dec * inten[c];
    }
    out[((b * 4 + p) << 16) + hw] = acc;   // x2 staged in the x4 slot
    mloc = fmaxf(mloc, acc);
  }

#pragma unroll
  for (int j = 0; j < NTAO; ++j)
    out[TAO_OFF + ((b * NTAO + j) << 16) + hw] = tg[j] * 0.25f;

  // wave-level max reduce, one atomic per wave (x2 >= 0 so uint order == float)
#pragma unroll
  for (int off = 32; off; off >>= 1) mloc = fmaxf(mloc, __shfl_xor(mloc, off));
  if ((tid & 63) == 0) atomicMax(wsmax, __builtin_bit_cast(unsigned int, mloc));
}

// ---------------------------------------------------------------------------
// Kernel C: noise + background patch -> x4 (in place over the staged x2)
// ---------------------------------------------------------------------------
__global__ __launch_bounds__(256) void kC(
    const float* __restrict__ bgf, float* __restrict__ out,
    const unsigned int* __restrict__ wsmax, PCParams pc) {
  const int e = blockIdx.x * 256 + threadIdx.x;   // [0, 524288)
  const int bp = e >> 16;                          // b*4+p in [0,8)
  const int rcc = e & 0xFFFF;
  const int r = rcc >> 8;
  const int cc = rcc & 255;

  const float x2 = out[e];
  const float mx = __builtin_bit_cast(float, *wsmax);
  const float xm = x2 / (mx + 0.0001f);

  // n_int = xm*NOISE_MU + NOISE_SIGMA*normal
  float n = normal_e(pc.kn0, pc.kn1, (uint32_t)e, (uint32_t)X4_SIZE);
  float n_int = xm * 5.0f + 1.0f * n;

  int pi = knuth_poisson(pc.s1, (uint32_t)e, fmaxf(xm, 0.0f));
  int po = knuth_poisson(pc.s2, (uint32_t)e, 2.0f);

  float x3 = ((n_int + (float)pi) + (float)po) + x2;

  // background patch: GRR[b,p, idx+r, cc]
  const int row = pc.idx + r;
  const int p = bp & 3;
  float bg = bgf[(p * BGH + row) * BGW + cc];
  const uint32_t ebg = (uint32_t)((bp * BGH + row) * BGW + cc);
  const uint32_t NBG = (uint32_t)(BB * PP) * (uint32_t)(BGH * BGW); // 85263872
  float nb = normal_e(pc.kb0, pc.kb1, ebg, NBG);
  float patch = (bg * pc.bg1[bp] + nb * pc.bg2[bp]) * 0.1f;

  float v = x3 + patch;
  v = fminf(fmaxf(v, 0.0f), 255.0f);
  out[e] = v / 255.0f;
}

// ---------------------------------------------------------------------------
// Host
// ---------------------------------------------------------------------------
extern "C" void kernel_launch(void* const* d_in, const int* in_sizes, int n_in,
                              void* d_out, int out_size, void* d_ws, size_t ws_size,
                              hipStream_t stream) {
  const float* x     = (const float*)d_in[0];
  const float* t     = (const float*)d_in[1];
  const float* ratio = (const float*)d_in[2];
  const float* life  = (const float*)d_in[3];
  const float* inten = (const float*)d_in[4];
  const float* bgf   = (const float*)d_in[5];
  float* out = (float*)d_out;
  unsigned int* wsmax = (unsigned int*)d_ws;

  // key(42) = (0,42) -> split into 9 subkeys
  uint32_t sk[9][2];
  jax_split(0u, 42u, 9, sk);
  // order: k_life, k_sig, k_norm, k_p1, k_p2, k_bg1, k_bg2, k_bgn, k_idx
  const uint32_t kl0 = sk[0][0], kl1 = sk[0][1];
  const uint32_t ks0 = sk[1][0], ks1 = sk[1][1];

  PCParams pc;
  pc.kn0 = sk[2][0]; pc.kn1 = sk[2][1];
  pc.kb0 = sk[7][0]; pc.kb1 = sk[7][1];

  // poisson knuth chains: rng, subkey = split(rng) each iteration
  {
    uint32_t r0 = sk[3][0], r1 = sk[3][1];
    for (int i = 0; i < NCH; ++i) {
      uint32_t two[2][2];
      jax_split(r0, r1, 2, two);
      pc.s1[2*i] = two[1][0]; pc.s1[2*i+1] = two[1][1];
      r0 = two[0][0]; r1 = two[0][1];
    }
    r0 = sk[4][0]; r1 = sk[4][1];
    for (int i = 0; i < NCH; ++i) {
      uint32_t two[2][2];
      jax_split(r0, r1, 2, two);
      pc.s2[2*i] = two[1][0]; pc.s2[2*i+1] = two[1][1];
      r0 = two[0][0]; r1 = two[0][1];
    }
  }

  // bg1, bg2: uniform(k, (2,4,1,1))*0.5 + 0.5  (xor-folded random_bits)
  for (uint32_t i = 0; i < 8; ++i) {
    pc.bg1[i] = u01(bits32(sk[5][0], sk[5][1], i, 8u)) * 0.5f + 0.5f;
    pc.bg2[i] = u01(bits32(sk[6][0], sk[6][1], i, 8u)) * 0.5f + 0.5f;
  }

  // idx = randint(k_idx, (), 0, 9): exact jax _randint double-word algorithm
  {
    uint32_t hi = bits32(sk[8][0], sk[8][1], 0u, 2u);
    uint32_t lo = bits32(sk[8][0], sk[8][1], 1u, 2u);
    const uint32_t span = 9u;
    uint32_t mult = (65536u % span);          // 2^16 % 9 = 7
    mult = (mult * mult) % span;              // 4
    uint32_t off = ((hi % span) * mult + (lo % span)) % span;
    pc.idx = (int)off;
  }

  kInit<<<1, 8, 0, stream>>>(t, ratio, out, wsmax);
  kA<<<(BB * HWSZ) / 256, 256, 0, stream>>>(x, t, ratio, life, inten, out, wsmax,
                                            kl0, kl1, ks0, ks1);
  kC<<<X4_SIZE / 256, 256, 0, stream>>>(bgf, out, wsmax, pc);
}

// Round 3
// 61.506 us; speedup vs baseline: 1.2131x; 1.2131x over previous
//
#include <hip/hip_runtime.h>
#include <cstdint>
#include <cstddef>

// ---------------------------------------------------------------------------
// Problem constants
// ---------------------------------------------------------------------------
#define BB 2
#define PP 4
#define CC 3
#define HWSZ 65536            // H*W
#define BGH 2764
#define BGW 3856
#define NTAO 27               // 3 lifes x 9 linspace points
#define X4_SIZE (BB*PP*HWSZ)              // 524288
#define TAO_OFF X4_SIZE
#define TAO_SIZE (BB*NTAO*HWSZ)           // 3538944
#define OUT2_OFF (TAO_OFF + TAO_SIZE)     // 4063232
#define NCH 40                            // poisson knuth chain depth

// ---------------------------------------------------------------------------
// Threefry-2x32-20 (matches jax/_src/prng.py, partitionable mode — verified r2)
// ---------------------------------------------------------------------------
__host__ __device__ inline void tf2x32(uint32_t k0, uint32_t k1,
                                       uint32_t x0, uint32_t x1,
                                       uint32_t& o0, uint32_t& o1) {
  uint32_t ks2 = k0 ^ k1 ^ 0x1BD11BDAu;
  x0 += k0; x1 += k1;
#define TF_RND(r) { x0 += x1; x1 = (x1 << (r)) | (x1 >> (32 - (r))); x1 ^= x0; }
  TF_RND(13) TF_RND(15) TF_RND(26) TF_RND(6)
  x0 += k1;  x1 += ks2 + 1u;
  TF_RND(17) TF_RND(29) TF_RND(16) TF_RND(24)
  x0 += ks2; x1 += k0 + 2u;
  TF_RND(13) TF_RND(15) TF_RND(26) TF_RND(6)
  x0 += k0;  x1 += k1 + 3u;
  TF_RND(17) TF_RND(29) TF_RND(16) TF_RND(24)
  x0 += k1;  x1 += ks2 + 4u;
  TF_RND(13) TF_RND(15) TF_RND(26) TF_RND(6)
  x0 += ks2; x1 += k0 + 5u;
#undef TF_RND
  o0 = x0; o1 = x1;
}

// 32-bit random bits for flat element e (partitionable: xor-fold of raw pair)
__host__ __device__ inline uint32_t bits32(uint32_t k0, uint32_t k1, uint32_t e) {
  uint32_t o0, o1;
  tf2x32(k0, k1, 0u, e, o0, o1);
  return o0 ^ o1;
}

// partitionable split: subkey i = RAW pair threefry(key, (0,i)) (no fold)
static void jax_split(uint32_t k0, uint32_t k1, int n, uint32_t (*keys)[2]) {
  for (int i = 0; i < n; ++i)
    tf2x32(k0, k1, 0u, (uint32_t)i, keys[i][0], keys[i][1]);
}

// bits -> float in [0,1)
__host__ __device__ inline float u01(uint32_t bits) {
  uint32_t fb = (bits >> 9) | 0x3F800000u;
  return __builtin_bit_cast(float, fb) - 1.0f;
}

// ---------------------------------------------------------------------------
// erfinv (Giles poly == XLA ErfInv32)
// ---------------------------------------------------------------------------
__device__ inline float erfinv_f(float x) {
  float w = -log1pf(-x * x);
  float p;
  if (w < 5.0f) {
    w = w - 2.5f;
    p = 2.81022636e-08f;
    p = fmaf(p, w, 3.43273939e-07f);
    p = fmaf(p, w, -3.5233877e-06f);
    p = fmaf(p, w, -4.39150654e-06f);
    p = fmaf(p, w, 0.00021858087f);
    p = fmaf(p, w, -0.00125372503f);
    p = fmaf(p, w, -0.00417768164f);
    p = fmaf(p, w, 0.246640727f);
    p = fmaf(p, w, 1.50140941f);
  } else {
    w = sqrtf(w) - 3.0f;
    p = -0.000200214257f;
    p = fmaf(p, w, 0.000100950558f);
    p = fmaf(p, w, 0.00134934322f);
    p = fmaf(p, w, -0.00367342844f);
    p = fmaf(p, w, 0.00573950773f);
    p = fmaf(p, w, -0.0076224613f);
    p = fmaf(p, w, 0.00943887047f);
    p = fmaf(p, w, 1.00167406f);
    p = fmaf(p, w, 2.83297682f);
  }
  return p * x;
}

__device__ inline float normal_e(uint32_t k0, uint32_t k1, uint32_t e) {
  float f = u01(bits32(k0, k1, e));
  const float LO = -0.99999994f;
  float u = fmaxf(LO, fmaf(f, 2.0f, LO));
  return 1.41421356237f * erfinv_f(u);
}

// ---------------------------------------------------------------------------
// Poisson via Knuth (per-lane early exit; force branchy loop, no unroll)
// ---------------------------------------------------------------------------
__device__ inline int knuth_poisson(const uint32_t* __restrict__ sk,
                                    uint32_t e, float lam) {
  if (!(lam > 0.0f)) return 0;
  const float neg = -lam;
  float lp = 0.0f;
  int k = 0;
#pragma clang loop unroll(disable)
  for (int i = 0; i < NCH; ++i) {
    if (!(lp > neg)) break;
    k++;
    float u = u01(bits32(sk[2*i], sk[2*i+1], e));
    lp += __logf(u);
  }
  return k - 1;
}

// ---------------------------------------------------------------------------
// Kernel params
// ---------------------------------------------------------------------------
struct PCParams {
  uint32_t kn0, kn1;        // k_norm
  uint32_t kb0, kb1;        // k_bgn
  uint32_t s1[NCH * 2];     // poisson chain subkeys for k_p1
  uint32_t s2[NCH * 2];     // poisson chain subkeys for k_p2
  float bg1[8], bg2[8];
  int idx;
};

// ---------------------------------------------------------------------------
// Kernel A: decay weights -> tao_gt + x2 (+ global max of x2)
// one thread per (b,hw); c-outer loop, only the 9 in-group taos per c
// (cross-group Gaussian weights <= exp(-36) ~ 1e-16: negligible vs 2e-2 thr)
// ---------------------------------------------------------------------------
__global__ __launch_bounds__(256) void kA(
    const float* __restrict__ x, const float* __restrict__ t,
    const float* __restrict__ ratio, const float* __restrict__ life,
    const float* __restrict__ inten, float* __restrict__ out,
    unsigned int* __restrict__ wsmax,
    uint32_t kl0, uint32_t kl1, uint32_t ks0, uint32_t ks1) {
  __shared__ float tao_s[NTAO];
  __shared__ float et_s[NTAO][4];
  __shared__ float life_s[3], inten_s[3];
  const int tid = threadIdx.x;
  if (tid < NTAO * 4) {
    int j = tid >> 2, p = tid & 3;
    float tao = life[j / 9] + (-40.0f + 10.0f * (float)(j % 9));
    float Tp = fmaxf(t[p] * ratio[p] * 1000.0f, 0.0f);
    et_s[j][p] = expf((-Tp) / tao);   // prologue only: keep libm accuracy
    if (p == 0) tao_s[j] = tao;
  }
  if (tid < 3) { life_s[tid] = life[tid]; inten_s[tid] = inten[tid]; }
  __syncthreads();

  const int g = blockIdx.x * 256 + tid;     // [0, 131072)
  const int b = g >> 16;
  const int hw = g & 0xFFFF;

  float acc4[4] = {0.0f, 0.0f, 0.0f, 0.0f};

#pragma clang loop unroll(disable)
  for (int c = 0; c < 3; ++c) {
    const float lifec = life_s[c];
    float tg9[9];
#pragma unroll
    for (int j = 0; j < 9; ++j) tg9[j] = 0.0f;

#pragma unroll
    for (int p = 0; p < 4; ++p) {
      const uint32_t e = (uint32_t)((((b * 4 + p) * 3 + c) << 16) + hw);
      float ul = u01(bits32(kl0, kl1, e));
      float Lr = lifec + ((ul - 0.5f) * 2.0f) * 6.0f;
      float us = u01(bits32(ks0, ks1, e));
      float sr = 6.0f + (((us - 0.5f) * 2.0f) * 6.0f) * 0.05f;
      float inv = 1.0f / (2.0f * sr * sr);
      float q[9];
      float s = 0.0f;
#pragma unroll
      for (int j = 0; j < 9; ++j) {
        float d = tao_s[c * 9 + j] - Lr;
        q[j] = __expf(-(d * d) * inv);
        s += q[j];
      }
      float rs = 1.0f / s;
      float dec = 0.0f;
#pragma unroll
      for (int j = 0; j < 9; ++j) {
        float wn = q[j] * rs;
        tg9[j] += wn;
        dec += et_s[c * 9 + j][p] * wn;
      }
      acc4[p] += x[e] * dec * inten_s[c];
    }

#pragma unroll
    for (int j = 0; j < 9; ++j)
      out[TAO_OFF + ((b * NTAO + c * 9 + j) << 16) + hw] = tg9[j] * 0.25f;
  }

  float mloc = 0.0f;
#pragma unroll
  for (int p = 0; p < 4; ++p) {
    out[((b * 4 + p) << 16) + hw] = acc4[p];   // x2 staged in the x4 slot
    mloc = fmaxf(mloc, acc4[p]);
  }

  // wave-level max reduce, one atomic per wave (x2 >= 0: uint order == float)
#pragma unroll
  for (int off = 32; off; off >>= 1) mloc = fmaxf(mloc, __shfl_xor(mloc, off));
  if ((tid & 63) == 0) atomicMax(wsmax, __builtin_bit_cast(unsigned int, mloc));
}

// ---------------------------------------------------------------------------
// Kernel C: noise + background patch -> x4 (in place over staged x2)
// block 0 also emits outputs 2 (t*ratio) and 3 (ratio)
// ---------------------------------------------------------------------------
__global__ __launch_bounds__(256) void kC(
    const float* __restrict__ bgf, const float* __restrict__ t,
    const float* __restrict__ ratio, float* __restrict__ out,
    const unsigned int* __restrict__ wsmax, PCParams pc) {
  const int e = blockIdx.x * 256 + threadIdx.x;   // [0, 524288)
  if (blockIdx.x == 0 && threadIdx.x < 8) {
    int i = threadIdx.x;
    out[OUT2_OFF + i] = (i < 4) ? t[i] * ratio[i] : ratio[i - 4];
  }
  const int bp = e >> 16;                          // b*4+p in [0,8)
  const int rcc = e & 0xFFFF;
  const int r = rcc >> 8;
  const int cc = rcc & 255;

  const float x2 = out[e];
  const float mx = __builtin_bit_cast(float, *wsmax);
  const float xm = x2 / (mx + 0.0001f);

  float n = normal_e(pc.kn0, pc.kn1, (uint32_t)e);
  float n_int = xm * 5.0f + 1.0f * n;

  int pi = knuth_poisson(pc.s1, (uint32_t)e, fmaxf(xm, 0.0f));
  int po = knuth_poisson(pc.s2, (uint32_t)e, 2.0f);

  float x3 = ((n_int + (float)pi) + (float)po) + x2;

  // background patch: GRR[b,p, idx+r, cc]
  const int row = pc.idx + r;
  const int p = bp & 3;
  float bg = bgf[(p * BGH + row) * BGW + cc];
  const uint32_t ebg = (uint32_t)((bp * BGH + row) * BGW + cc);
  float nb = normal_e(pc.kb0, pc.kb1, ebg);
  float patch = (bg * pc.bg1[bp] + nb * pc.bg2[bp]) * 0.1f;

  float v = x3 + patch;
  v = fminf(fmaxf(v, 0.0f), 255.0f);
  out[e] = v / 255.0f;
}

// ---------------------------------------------------------------------------
// Host
// ---------------------------------------------------------------------------
extern "C" void kernel_launch(void* const* d_in, const int* in_sizes, int n_in,
                              void* d_out, int out_size, void* d_ws, size_t ws_size,
                              hipStream_t stream) {
  const float* x     = (const float*)d_in[0];
  const float* t     = (const float*)d_in[1];
  const float* ratio = (const float*)d_in[2];
  const float* life  = (const float*)d_in[3];
  const float* inten = (const float*)d_in[4];
  const float* bgf   = (const float*)d_in[5];
  float* out = (float*)d_out;
  unsigned int* wsmax = (unsigned int*)d_ws;

  // key(42) = (0,42) -> 9 subkeys:
  // k_life, k_sig, k_norm, k_p1, k_p2, k_bg1, k_bg2, k_bgn, k_idx
  uint32_t sk[9][2];
  jax_split(0u, 42u, 9, sk);

  PCParams pc;
  pc.kn0 = sk[2][0]; pc.kn1 = sk[2][1];
  pc.kb0 = sk[7][0]; pc.kb1 = sk[7][1];

  // poisson knuth chains: rng, subkey = split(rng) per iteration
  {
    uint32_t r0 = sk[3][0], r1 = sk[3][1];
    for (int i = 0; i < NCH; ++i) {
      uint32_t two[2][2];
      jax_split(r0, r1, 2, two);
      pc.s1[2*i] = two[1][0]; pc.s1[2*i+1] = two[1][1];
      r0 = two[0][0]; r1 = two[0][1];
    }
    r0 = sk[4][0]; r1 = sk[4][1];
    for (int i = 0; i < NCH; ++i) {
      uint32_t two[2][2];
      jax_split(r0, r1, 2, two);
      pc.s2[2*i] = two[1][0]; pc.s2[2*i+1] = two[1][1];
      r0 = two[0][0]; r1 = two[0][1];
    }
  }

  for (uint32_t i = 0; i < 8; ++i) {
    pc.bg1[i] = u01(bits32(sk[5][0], sk[5][1], i)) * 0.5f + 0.5f;
    pc.bg2[i] = u01(bits32(sk[6][0], sk[6][1], i)) * 0.5f + 0.5f;
  }

  // idx = randint(k_idx, (), 0, 9): exact jax _randint double-word algorithm
  {
    uint32_t hi = bits32(sk[8][0], sk[8][1], 0u);
    uint32_t lo = bits32(sk[8][0], sk[8][1], 1u);
    const uint32_t span = 9u;
    uint32_t mult = (65536u % span);          // 7
    mult = (mult * mult) % span;              // 4
    uint32_t off = ((hi % span) * mult + (lo % span)) % span;
    pc.idx = (int)off;
  }

  hipMemsetAsync(d_ws, 0, 4, stream);
  kA<<<(BB * HWSZ) / 256, 256, 0, stream>>>(x, t, ratio, life, inten, out, wsmax,
                                            sk[0][0], sk[0][1], sk[1][0], sk[1][1]);
  kC<<<X4_SIZE / 256, 256, 0, stream>>>(bgf, t, ratio, out, wsmax, pc);
}